// Round 4
// baseline (510.934 us; speedup 1.0000x reference)
//
#include <hip/hip_runtime.h>

// DCT upsample: out[img] = M * x[img] * M^T,  M = E*D (960x768), closed-form
// Dirichlet kernel:
//   M[i][n] = (1 + S(p1) + S(p2))/960,  S = sin(767u)cos(768u)/sin(u), u=pi*p/15360
// Restructured so M is the A operand of BOTH gemms:
//   T' = M * x^T      (Bt = xb bf16, separate conv pass)   [960 x 768]
//   out = M * T'^T    (Bt = T')                            [960 x 960]
// V5: 256x256 8-wave kernel, read-ahead pipelined quadrant schedule +
// persistent blocks:
//   - Per K-tile, 4 quadrant phases; each quadrant's ds_reads are issued one
//     phase EARLY under the previous quadrant's MFMA burst (compiler inserts
//     counted lgkmcnt). Quadrant rotation makes fragment double-buffering
//     free: afr0/bf0 are dead after Q01/Q10, so P4 preloads next tile's Q00
//     operands from the freshly published buffer. 4 barriers/tile (was 8),
//     zero serial LDS exposure in steady state.
//   - Persistent: grid = 256 blocks, each walks assignments a, a+256, ...;
//     at t=NT-1 the staging pointers switch to the next assignment's tile 0,
//     so the glds pipeline NEVER drains; epilogue overlaps the next tile-0
//     loads already in flight.
//   - Clamp-free staging: A (M-matrix) and B (ws buffers) are padded by 64
//     rows, so OOB staging reads garbage that is discarded by the epilogue
//     bounds check (garbage rows/cols only poison discarded C rows/cols).
//   - XOR chunk swizzle as V3: phys 16B-chunk p of row r holds logical
//     p^((r>>1)&7), applied on the per-lane global source (LDS dest linear);
//     fragment reads apply the same XOR -> conflict-free (measured 0).

#define HW 768
#define OHW 960
#define NIMG 48
#define NTILES 12   // K = 768 / BK=64

typedef __attribute__((ext_vector_type(8))) short short8;
typedef __attribute__((ext_vector_type(4))) float f32x4;
typedef __attribute__((ext_vector_type(4))) float float4v;
typedef __attribute__((ext_vector_type(4))) unsigned short us4;

__device__ __forceinline__ unsigned short f2bf(float f) {
    union { float f; unsigned int u; } v; v.f = f;
    unsigned int u = v.u;
    return (unsigned short)((u + 0x7FFFu + ((u >> 16) & 1u)) >> 16);
}

__device__ __forceinline__ void glds16(const void* g, void* l) {
    __builtin_amdgcn_global_load_lds(
        (const __attribute__((address_space(1))) void*)g,
        (__attribute__((address_space(3))) void*)l, 16, 0, 0);
}

// ---------------- closed-form M fill ----------------
__device__ __forceinline__ float dsum(int p) {
    int n1 = (767 * p) % 30720;
    int n2 = (768 * p) % 30720;
    const float w = (float)(3.14159265358979323846 / 15360.0);
    return sinf((float)n1 * w) * cosf((float)n2 * w) / sinf((float)p * w);
}

__global__ void fill_M(unsigned short* __restrict__ Mb) {
    int idx = blockIdx.x * 256 + threadIdx.x;
    if (idx >= OHW * HW) return;
    int i = idx / HW, n = idx - i * HW;
    int a = 8 * i + 4, b = 10 * n + 5;
    int p1 = a + b;
    int p2 = a - b; if (p2 < 0) p2 += 15360;
    float m = (1.0f + dsum(p1) + dsum(p2)) * (1.0f / 960.0f);
    Mb[idx] = f2bf(m);
}

// ---------------- streaming f32 -> bf16 convert ----------------
__global__ void conv_bf16(const float* __restrict__ x, unsigned short* __restrict__ xb, int n4) {
    int i = blockIdx.x * 256 + threadIdx.x;
    if (i >= n4) return;
    float4v v = *(const float4v*)(x + (size_t)i * 4);
    us4 o; o.x = f2bf(v.x); o.y = f2bf(v.y); o.z = f2bf(v.z); o.w = f2bf(v.w);
    *(us4*)(xb + (size_t)i * 4) = o;
}

// ---------------- MFMA GEMM (B-transposed, K-major operands) ----------------
#define ASM_BAR   asm volatile("s_barrier" ::: "memory")
#define ASM_VM0   asm volatile("s_waitcnt vmcnt(0)" ::: "memory")

__global__ __launch_bounds__(512, 2) void gemm_bt(
    const unsigned short* __restrict__ A, int lda,
    const unsigned short* __restrict__ Bg, long long strideB, int ldb,
    void* __restrict__ Cg, long long strideC, int ldc,
    int Md, int Nd, int out_f32, int gx, int gy, int nA)
{
    __shared__ unsigned short As[2][256 * 64];
    __shared__ unsigned short Bs[2][256 * 64];

    const int tid = threadIdx.x;
    const int wave = tid >> 6, lane = tid & 63;
    const int wm = wave >> 2, wn = wave & 3;     // 2 x 4 wave grid
    const int t16 = lane & 15, quad = lane >> 4;
    const int nB = gridDim.x;

    int a = blockIdx.x;
    if (a >= nA) return;

    // ---- per-lane loop-invariant staging offsets (elements) ----
    // 16B-chunk c = tid + 512*j -> row r = c>>3, phys p = tid&7,
    // logical chunk l = p ^ ((r>>1)&7) = (tid&7)^((tid>>4)&7)
    const int srow = tid >> 3;                             // 0..63
    const int klog = ((tid & 7) ^ ((tid >> 4) & 7)) * 8;
    int invA[4], invB[4];
#pragma unroll
    for (int j = 0; j < 4; ++j) {
        invA[j] = (srow + 64 * j) * lda + klog;
        invB[j] = (srow + 64 * j) * ldb + klog;
    }
    const int dOff = tid * 8;

    // ---- fragment read offsets (shorts) ----
    const int swz = (t16 >> 1) & 7;
    const int ph0 = (quad ^ swz) * 8;
    const int ph1 = ((4 + quad) ^ swz) * 8;
    const int aRow = (wm * 128 + t16) * 64;
    const int bRow = (wn * 64 + t16) * 64;

    f32x4 acc[8][4];
#pragma unroll
    for (int i = 0; i < 8; ++i)
#pragma unroll
        for (int j = 0; j < 4; ++j)
            acc[i][j] = (f32x4){0.f, 0.f, 0.f, 0.f};

    // ---- scalar assignment decode (no clamps: ws buffers are padded) ----
    int mb, nbb, zz; long long offA, offB;
#define DECODE(aa) do { int gxy_ = gx * gy; zz = (aa) / gxy_;                  \
    int r_ = (aa) - zz * gxy_; int by_ = r_ / gx; int bx_ = r_ - by_ * gx;     \
    mb = by_ * 256; nbb = bx_ * 256;                                           \
    offA = (long long)mb * lda;                                                \
    offB = (long long)zz * strideB + (long long)nbb * ldb; } while (0)

    DECODE(a);

#define STG_A(buf, stk) do { _Pragma("unroll")                                 \
    for (int j_ = 0; j_ < 4; ++j_)                                             \
        glds16(A + offA + invA[j_] + (stk),                                    \
               &As[buf][0] + dOff + j_ * 4096); } while (0)
#define STG_B(buf, stk) do { _Pragma("unroll")                                 \
    for (int j_ = 0; j_ < 4; ++j_)                                             \
        glds16(Bg + offB + invB[j_] + (stk),                                   \
               &Bs[buf][0] + dOff + j_ * 4096); } while (0)

    short8 afr0[4][2], afr1[4][2], bf0[2][2], bf1[2][2];

#define RD_A(dst, base, mig) do { _Pragma("unroll")                            \
    for (int mi_ = 0; mi_ < 4; ++mi_) {                                        \
        dst[mi_][0] = *(const short8*)((base) + aRow + ((mig)*4+mi_)*1024 + ph0); \
        dst[mi_][1] = *(const short8*)((base) + aRow + ((mig)*4+mi_)*1024 + ph1); \
    } } while (0)
#define RD_B(dst, base, nig) do { _Pragma("unroll")                            \
    for (int ni_ = 0; ni_ < 2; ++ni_) {                                        \
        dst[ni_][0] = *(const short8*)((base) + bRow + ((nig)*2+ni_)*1024 + ph0); \
        dst[ni_][1] = *(const short8*)((base) + bRow + ((nig)*2+ni_)*1024 + ph1); \
    } } while (0)

#define MMA_Q(mig, nig, av, bv) do {                                           \
    __builtin_amdgcn_s_setprio(1);                                             \
    _Pragma("unroll")                                                          \
    for (int ks_ = 0; ks_ < 2; ++ks_)                                          \
    _Pragma("unroll")                                                          \
    for (int mi_ = 0; mi_ < 4; ++mi_)                                          \
    _Pragma("unroll")                                                          \
    for (int ni_ = 0; ni_ < 2; ++ni_)                                          \
        acc[(mig)*4+mi_][(nig)*2+ni_] =                                        \
            __builtin_amdgcn_mfma_f32_16x16x32_bf16(                           \
                av[mi_][ks_], bv[ni_][ks_],                                    \
                acc[(mig)*4+mi_][(nig)*2+ni_], 0, 0, 0);                       \
    __builtin_amdgcn_s_setprio(0); } while (0)

    // ---- prologue: stage tile 0 into buf 0, preload Q00 fragments ----
    STG_A(0, 0); STG_B(0, 0);
    ASM_VM0; ASM_BAR;
    RD_A(afr0, &As[0][0], 0);
    RD_B(bf0, &Bs[0][0], 0);

    for (;;) {
        const int emb = mb, enb = nbb, ez = zz;   // epilogue coords
#pragma unroll 2
        for (int t = 0; t < NTILES; ++t) {
            const int c = t & 1, n = c ^ 1;
            const unsigned short* Asc = &As[c][0];
            const unsigned short* Bsc = &Bs[c][0];
            bool pf = true; int stk = (t + 1) * 64;
            if (t == NTILES - 1) {
                if (a + nB < nA) { DECODE(a + nB); stk = 0; }
                else pf = false;
            }
            // P1: stage A(next) | read bf1 | MFMA Q00 (afr0,bf0 preloaded)
            if (pf) STG_A(n, stk);
            RD_B(bf1, Bsc, 1);
            MMA_Q(0, 0, afr0, bf0);
            ASM_BAR;
            // P2: stage B(next) | read afr1 | MFMA Q01
            if (pf) STG_B(n, stk);
            RD_A(afr1, Asc, 1);
            MMA_Q(0, 1, afr0, bf1);
            ASM_BAR;
            // P3: MFMA Q10 | publish next buffer (vm0 after ~2 phases cover)
            MMA_Q(1, 0, afr1, bf0);
            ASM_VM0;
            ASM_BAR;
            // P4: preload next tile's Q00 fragments | MFMA Q11
            if (pf) { RD_A(afr0, &As[n][0], 0); RD_B(bf0, &Bs[n][0], 0); }
            MMA_Q(1, 1, afr1, bf1);
            ASM_BAR;
        }

        // ---- epilogue: D row = quad*4 + r, col = t16 per 16x16 tile ----
        const int gr0 = emb + wm * 128;
        const int gc0 = enb + wn * 64;
        if (out_f32) {
            float* C = (float*)Cg + (size_t)ez * strideC;
#pragma unroll
            for (int mi = 0; mi < 8; ++mi)
#pragma unroll
                for (int ni = 0; ni < 4; ++ni) {
                    int col = gc0 + ni * 16 + t16;
                    if (col < Nd) {
#pragma unroll
                        for (int r = 0; r < 4; ++r) {
                            int rowg = gr0 + mi * 16 + quad * 4 + r;
                            if (rowg < Md) C[(size_t)rowg * ldc + col] = acc[mi][ni][r];
                        }
                    }
                }
        } else {
            unsigned short* C = (unsigned short*)Cg + (size_t)ez * strideC;
#pragma unroll
            for (int mi = 0; mi < 8; ++mi)
#pragma unroll
                for (int ni = 0; ni < 4; ++ni) {
                    int col = gc0 + ni * 16 + t16;
                    if (col < Nd) {
#pragma unroll
                        for (int r = 0; r < 4; ++r) {
                            int rowg = gr0 + mi * 16 + quad * 4 + r;
                            if (rowg < Md) C[(size_t)rowg * ldc + col] = f2bf(acc[mi][ni][r]);
                        }
                    }
                }
        }

        a += nB;
        if (a >= nA) break;
#pragma unroll
        for (int i = 0; i < 8; ++i)
#pragma unroll
            for (int j = 0; j < 4; ++j)
                acc[i][j] = (f32x4){0.f, 0.f, 0.f, 0.f};
    }
}

extern "C" void kernel_launch(void* const* d_in, const int* in_sizes, int n_in,
                              void* d_out, int out_size, void* d_ws, size_t ws_size,
                              hipStream_t stream) {
    const float* x = (const float*)d_in[0];
    float* out = (float*)d_out;
    char* ws = (char*)d_ws;

    // padded allocations: staging may read up to 64 rows past the logical end
    size_t szM   = (size_t)(OHW + 64) * HW * 2;              // 1,572,864 B
    size_t fixed = szM;
    size_t perImgX = (size_t)HW * HW * 2;
    size_t perImgT = (size_t)OHW * HW * 2;
    size_t padT  = (size_t)64 * HW * 2;                      // 98,304 B

    int nb = 1;
    if (ws_size > fixed + perImgX + perImgT + padT) {
        size_t q = (ws_size - fixed - padT) / (perImgX + perImgT);
        nb = (q > 48) ? 48 : (int)q;
        if (nb < 1) nb = 1;
    }

    unsigned short* Mb = (unsigned short*)(ws + 0);
    unsigned short* xb = (unsigned short*)(ws + fixed);
    unsigned short* T  = (unsigned short*)(ws + fixed + (size_t)nb * perImgX);

    fill_M<<<(OHW * HW + 255) / 256, 256, 0, stream>>>(Mb);

    for (int b0 = 0; b0 < NIMG; b0 += nb) {
        int cur = NIMG - b0; if (cur > nb) cur = nb;
        // xb = bf16(x[b0..b0+cur]), streaming convert
        int n4 = cur * (HW * HW / 4);
        conv_bf16<<<(n4 + 255) / 256, 256, 0, stream>>>(
            x + (size_t)b0 * HW * HW, xb, n4);
        // T' = M * x^T : A = M [960x768], Bt = xb, persistent grid
        {
            int gx = 3, gy = 4, nA = gx * gy * cur;
            int nblk = nA < 256 ? nA : 256;
            gemm_bt<<<dim3(nblk), 512, 0, stream>>>(
                Mb, HW, xb, (long long)HW * HW, HW,
                T, (long long)OHW * HW, HW, OHW, HW, 0, gx, gy, nA);
        }
        // out = M * T'^T : A = M, Bt = T', persistent grid
        {
            int gx = 4, gy = 4, nA = gx * gy * cur;
            int nblk = nA < 256 ? nA : 256;
            gemm_bt<<<dim3(nblk), 512, 0, stream>>>(
                Mb, HW, T, (long long)OHW * HW, HW,
                out + (size_t)b0 * OHW * OHW, (long long)OHW * OHW, OHW,
                OHW, OHW, 1, gx, gy, nA);
        }
    }
    (void)in_sizes; (void)n_in; (void)out_size;
}